// Round 16
// baseline (123.585 us; speedup 1.0000x reference)
//
#include <hip/hip_runtime.h>

// Sizes (fixed by the problem)
#define BB 4
#define CC 256
#define HH 128
#define WW 128
#define HP 64          // pooled H, W
#define NP 4096        // HP*HP tokens per batch

#define L2E 1.4426950408889634f

typedef __attribute__((ext_vector_type(4)))  float f32x4;
typedef __attribute__((ext_vector_type(16))) float f32x16;
typedef __attribute__((ext_vector_type(8)))  short bf16x8;       // 8 bf16 in 4 VGPRs
typedef __attribute__((ext_vector_type(4)))  unsigned int u32x4;
typedef __attribute__((ext_vector_type(2)))  __bf16 bf16x2_t;

// 2^x via v_exp_f32 (native). NOT __exp2f: that name collides with glibc macros.
static __device__ __forceinline__ float exp2fast(float x) {
    return __builtin_amdgcn_exp2f(x);
}

// float -> bf16 bits, round-to-nearest-even bit-trick (used on proj/pool paths).
static __device__ __forceinline__ unsigned short f2bf(float f) {
    unsigned int u = __float_as_uint(f);
    u = (u + 0x7FFFu + ((u >> 16) & 1u)) >> 16;
    return (unsigned short)u;
}
// flash P-pack: compiler-fused v_cvt_pk_bf16_f32 (plain casts, no asm — m240).
static __device__ __forceinline__ unsigned int pk2(float a, float b) {
    bf16x2_t v = {(__bf16)a, (__bf16)b};
    return __builtin_bit_cast(unsigned int, v);
}

// ---------------------------------------------------------------------------
// Fragment-ordered layouts (bf16):
//   xfrag[b][nt(128)][ks(16)][lane(64)][e(8)] : B-frag, X[c][n]
//   wfrag[ot(10)][ks(16)][lane(64)][e(8)]     : A-frag, W[o][c] (Q rows xL2E)
//   Q2[qtile(128)][f(2)][q(32)][hi(2)][e(8)]
//   K2[kchunk(128)][f(2)][k(32)][hi(2)][e(8)]
//   V2[kc(128)][w2(2)][ctg(8)][q(32)][hi(2)][e(8)]
// mfma_32x32x16_bf16 (m74/m101): A row=lane&31, k=(lane>>5)*8+e; B col=lane&31,
// same k; D col=lane&31, row=(r&3)+8*(r>>2)+4*(lane>>5).
// ---------------------------------------------------------------------------

// ---------------------------------------------------------------------------
// K1: fused 2x2 avg-pool + bf16 B-fragment layout, PLUS (blocks >= 2048)
// the one-time W -> A-fragment reorder (merged to save a launch).
// ---------------------------------------------------------------------------
__global__ __launch_bounds__(256) void prep_kernel(const float* __restrict__ x,
                                                   const float* __restrict__ wq,
                                                   const float* __restrict__ wk,
                                                   const float* __restrict__ wv,
                                                   unsigned short* __restrict__ xfrag,
                                                   unsigned short* __restrict__ wfrag) {
    if (blockIdx.x < 2048) {
        int tid  = blockIdx.x * 256 + threadIdx.x;   // 4*128*16*64 = 524,288 threads
        int lane = tid & 63;
        int ks   = (tid >> 6) & 15;
        int nt   = (tid >> 10) & 127;
        int b    = tid >> 17;

        int n  = nt * 32 + (lane & 31);
        int c0 = ks * 16 + (lane >> 5) * 8;
        int hp = n >> 6, wp = n & 63;

        const float* xb = x + (size_t)b * CC * (HH * WW) + (2 * hp) * WW + 2 * wp;
        unsigned short r[8];
        #pragma unroll
        for (int e = 0; e < 8; e++) {
            const float* src = xb + (size_t)(c0 + e) * (HH * WW);
            float2 a = *(const float2*)(src);
            float2 d = *(const float2*)(src + WW);
            r[e] = f2bf(0.25f * (a.x + a.y + d.x + d.y));
        }
        ushort4 lo = (ushort4){r[0], r[1], r[2], r[3]};
        ushort4 hi = (ushort4){r[4], r[5], r[6], r[7]};
        *(ushort4*)(xfrag + (size_t)tid * 8)     = lo;
        *(ushort4*)(xfrag + (size_t)tid * 8 + 4) = hi;
    } else {
        int tid  = (blockIdx.x - 2048) * 256 + threadIdx.x;   // 10*16*64 = 10,240
        if (tid >= 10240) return;
        int lane = tid & 63;
        int ks   = (tid >> 6) & 15;
        int ot   = tid >> 10;

        int o = ot * 32 + (lane & 31);
        int c = ks * 16 + (lane >> 5) * 8;
        const float* wrow;
        float scale = 1.0f;
        if (o < 32)      { wrow = wq + (size_t)o * CC;        scale = L2E; }
        else if (o < 64) { wrow = wk + (size_t)(o - 32) * CC; }
        else             { wrow = wv + (size_t)(o - 64) * CC; }
        float4 w0 = *(const float4*)(wrow + c);
        float4 w1 = *(const float4*)(wrow + c + 4);
        ushort4 lo = {f2bf(w0.x * scale), f2bf(w0.y * scale), f2bf(w0.z * scale), f2bf(w0.w * scale)};
        ushort4 hi = {f2bf(w1.x * scale), f2bf(w1.y * scale), f2bf(w1.z * scale), f2bf(w1.w * scale)};
        *(ushort4*)(wfrag + (size_t)tid * 8)     = lo;
        *(ushort4*)(wfrag + (size_t)tid * 8 + 4) = hi;
    }
}

// ---------------------------------------------------------------------------
// K2: MFMA projection GEMM. Block = 2 waves; wave computes one 32o x 32n
// tile over K=256 (16 MFMA). All operand loads are contiguous 1KB/wave.
// Epilogue adds bias and scatter-stores into Q2/K2/V2 fragment layouts.
// ---------------------------------------------------------------------------
__global__ __launch_bounds__(128) void projm_kernel(const unsigned short* __restrict__ xfrag,
                                                    const unsigned short* __restrict__ wfrag,
                                                    const float* __restrict__ bq,
                                                    const float* __restrict__ bk,
                                                    const float* __restrict__ bv,
                                                    unsigned short* __restrict__ qarr,
                                                    unsigned short* __restrict__ karr,
                                                    unsigned short* __restrict__ varr) {
    int j    = blockIdx.x;            // 4b * 128nt * 5og = 2560
    int og   = j % 5;
    int nt   = (j / 5) & 127;
    int b    = j / 640;
    int lane = threadIdx.x & 63;
    int ot   = og * 2 + (threadIdx.x >> 6);   // 0..9

    const unsigned short* abase = wfrag + ((size_t)ot * 16 * 64 + lane) * 8;
    const unsigned short* bbase = xfrag + (((size_t)(b * 128 + nt) * 16) * 64 + lane) * 8;

    f32x16 acc;
    #pragma unroll
    for (int r = 0; r < 16; r++) acc[r] = 0.f;

    #pragma unroll
    for (int ks = 0; ks < 16; ks++) {
        bf16x8 af = *(const bf16x8*)(abase + (size_t)ks * 512);
        bf16x8 bf = *(const bf16x8*)(bbase + (size_t)ks * 512);
        acc = __builtin_amdgcn_mfma_f32_32x32x16_bf16(af, bf, acc, 0, 0, 0);
    }

    int l31 = lane & 31;
    int hi2 = lane >> 5;

    if (ot == 0) {
        unsigned short* qb = qarr + (size_t)b * (NP * 32);
        #pragma unroll
        for (int r = 0; r < 16; r++) {
            int o = (r & 3) + 8 * (r >> 2) + 4 * hi2;
            float v = acc[r] + bq[o] * L2E;
            size_t idx = (((size_t)nt * 2 + (o >> 4)) * 32 + l31) * 16 + ((o >> 3) & 1) * 8 + (o & 7);
            qb[idx] = f2bf(v);
        }
    } else if (ot == 1) {
        unsigned short* kb = karr + (size_t)b * (NP * 32);
        #pragma unroll
        for (int r = 0; r < 16; r++) {
            int o = (r & 3) + 8 * (r >> 2) + 4 * hi2;
            float v = acc[r] + bk[o];
            size_t idx = (((size_t)nt * 2 + (o >> 4)) * 32 + l31) * 16 + ((o >> 3) & 1) * 8 + (o & 7);
            kb[idx] = f2bf(v);
        }
    } else {
        unsigned short* vb = varr + (size_t)b * (CC * NP);
        int kc = nt, w2 = (l31 >> 4) & 1, hiv = (l31 >> 3) & 1, ev = l31 & 7;
        size_t base = (((size_t)kc * 2 + w2) * 8) * 32 * 16 + hiv * 8 + ev;
        #pragma unroll
        for (int r = 0; r < 16; r++) {
            int c = (ot - 2) * 32 + (r & 3) + 8 * (r >> 2) + 4 * hi2;
            float v = acc[r] + bv[c];
            size_t idx = base + ((size_t)(c >> 5) * 32 + (c & 31)) * 16;
            vb[idx] = f2bf(v);
        }
    }
}

// ---------------------------------------------------------------------------
// K3: swapped-operand 32x32 MFMA flash attention, FULL-CHANNEL waves,
// DEPTH-2 V PIPELINE: vfA/vfB halves are refilled with chunk k+1's fragments
// immediately after PV consumes them -> each V load gets ~600+cy of cover
// (PV-half + QK + softmax) instead of ~250 (R15's same-iteration hoist).
// Register-neutral (same 16 staging regs). K stays 1 chunk ahead.
// ---------------------------------------------------------------------------
__global__ __launch_bounds__(256, 2) void flash32_kernel(const unsigned short* __restrict__ qarr,
                                                         const unsigned short* __restrict__ karr,
                                                         const unsigned short* __restrict__ varr,
                                                         float* __restrict__ att) {
    __shared__ float cacc[64][140];    // combine: 128 f32/lane (140: 8-way not 16-way bank conflict)
    __shared__ float cml[64][2];       // combine: m, l per lane
    int t    = threadIdx.x;
    int lane = t & 63;
    int ks   = t >> 6;                 // 0..3 key quarter
    int j    = blockIdx.x;
    int b    = j & 3;                  // batch -> XCD pinning
    int qt   = j >> 2;                 // 0..127 q-tile (32 rows)

    const unsigned short* qb2 = qarr + (size_t)b * (NP * 32);
    const unsigned short* kb2 = karr + (size_t)b * (NP * 32);
    const unsigned short* vb2 = varr + (size_t)b * (CC * NP);

    int q  = lane & 31;
    int hi = lane >> 5;
    int lq16 = (q * 2 + hi) * 8;       // lane's 16B slot within a 1KB fragment block

    bf16x8 qf0 = *(const bf16x8*)(qb2 + (size_t)(qt * 2 + 0) * 512 + lq16);
    bf16x8 qf1 = *(const bf16x8*)(qb2 + (size_t)(qt * 2 + 1) * 512 + lq16);

    f32x16 acc[8];
    #pragma unroll
    for (int ct = 0; ct < 8; ct++)
        #pragma unroll
        for (int r = 0; r < 16; r++) acc[ct][r] = 0.f;
    float mrun = -3.0e38f, lrun = 0.f;

    const f32x16 z16 = {0.f,0.f,0.f,0.f,0.f,0.f,0.f,0.f,0.f,0.f,0.f,0.f,0.f,0.f,0.f,0.f};

    // ---- prologue: K + both V halves for first chunk
    int kc0 = ks * 32;
    const unsigned short* kcp0 = kb2 + (size_t)kc0 * 1024 + lq16;
    bf16x8 kcur0 = *(const bf16x8*)(kcp0);
    bf16x8 kcur1 = *(const bf16x8*)(kcp0 + 512);
    bf16x8 vfA[8], vfB[8];
    {
        const unsigned short* vcp0 = vb2 + ((size_t)kc0 * 16) * 512 + lq16;
        #pragma unroll
        for (int i = 0; i < 8; i++) vfA[i] = *(const bf16x8*)(vcp0 + (size_t)i * 512);
        #pragma unroll
        for (int i = 0; i < 8; i++) vfB[i] = *(const bf16x8*)(vcp0 + (size_t)(8 + i) * 512);
    }

    for (int kci = 0; kci < 32; ++kci) {
        int kcidx = kc0 + kci;
        int nid = (kci < 31) ? (kcidx + 1) : kcidx;   // clamp: last iter reloads

        // ---- K loads for NEXT chunk (consumed next iteration)
        const unsigned short* kn = kb2 + (size_t)nid * 1024 + lq16;
        bf16x8 kn0 = *(const bf16x8*)(kn);
        bf16x8 kn1 = *(const bf16x8*)(kn + 512);

        // ---- QK^T swapped (operands loaded one iteration ago)
        f32x16 s = __builtin_amdgcn_mfma_f32_32x32x16_bf16(kcur0, qf0, z16, 0, 0, 0);
        s = __builtin_amdgcn_mfma_f32_32x32x16_bf16(kcur1, qf1, s, 0, 0, 0);

        // ---- in-lane max over 16 keys + 1 cross-half swap
        float m01 = fmaxf(s[0], s[1]),   m23 = fmaxf(s[2], s[3]);
        float m45 = fmaxf(s[4], s[5]),   m67 = fmaxf(s[6], s[7]);
        float m89 = fmaxf(s[8], s[9]),   mab = fmaxf(s[10], s[11]);
        float mcd = fmaxf(s[12], s[13]), mef = fmaxf(s[14], s[15]);
        float mx = fmaxf(fmaxf(fmaxf(m01, m23), fmaxf(m45, m67)),
                         fmaxf(fmaxf(m89, mab), fmaxf(mcd, mef)));
        mx = fmaxf(mx, __shfl_xor(mx, 32, 64));

        // ---- defer-max (T13, log2 domain)
        if (!__all(mx - mrun <= 11.5f)) {
            float mn = fmaxf(mrun, mx);
            float sc = exp2fast(mrun - mn);
            mrun = mn;
            lrun *= sc;
            #pragma unroll
            for (int ct = 0; ct < 8; ct++)
                #pragma unroll
                for (int r = 0; r < 16; r++) acc[ct][r] *= sc;
        }

        // ---- P = exp2(S^T - m): cvt_pk pack + depth-4 tree sum
        unsigned int pkr[8];
        float ps[8];
        #pragma unroll
        for (int r2 = 0; r2 < 8; r2++) {
            float p0 = exp2fast(s[2 * r2]     - mrun);
            float p1 = exp2fast(s[2 * r2 + 1] - mrun);
            ps[r2] = p0 + p1;
            pkr[r2] = pk2(p0, p1);
        }
        float s01 = ps[0] + ps[1], s23 = ps[2] + ps[3];
        float s45 = ps[4] + ps[5], s67 = ps[6] + ps[7];
        float ss = (s01 + s23) + (s45 + s67);
        ss += __shfl_xor(ss, 32, 64);
        lrun += ss;

        const unsigned short* vnp = vb2 + ((size_t)nid * 16) * 512 + lq16;

        // ---- PV half 0 (vfA, loaded one iteration ago), then refill vfA
        {
            unsigned int a0 = pkr[0], a1 = pkr[1];
            unsigned int c0 = pkr[2], c1 = pkr[3];
            unsigned int sa0 = __shfl_xor(a0, 32, 64), sa1 = __shfl_xor(a1, 32, 64);
            unsigned int sc0 = __shfl_xor(c0, 32, 64), sc1 = __shfl_xor(c1, 32, 64);
            u32x4 fr;
            if (hi == 0) { fr[0] = a0;  fr[1] = a1;  fr[2] = sa0; fr[3] = sa1; }
            else         { fr[0] = sc0; fr[1] = sc1; fr[2] = c0;  fr[3] = c1;  }
            bf16x8 pf = __builtin_bit_cast(bf16x8, fr);
            #pragma unroll
            for (int ct = 0; ct < 8; ct++)
                acc[ct] = __builtin_amdgcn_mfma_f32_32x32x16_bf16(vfA[ct], pf, acc[ct], 0, 0, 0);
            #pragma unroll
            for (int i = 0; i < 8; i++)
                vfA[i] = *(const bf16x8*)(vnp + (size_t)i * 512);
        }

        // ---- PV half 1 (vfB), then refill vfB
        {
            unsigned int a0 = pkr[4], a1 = pkr[5];
            unsigned int c0 = pkr[6], c1 = pkr[7];
            unsigned int sa0 = __shfl_xor(a0, 32, 64), sa1 = __shfl_xor(a1, 32, 64);
            unsigned int sc0 = __shfl_xor(c0, 32, 64), sc1 = __shfl_xor(c1, 32, 64);
            u32x4 fr;
            if (hi == 0) { fr[0] = a0;  fr[1] = a1;  fr[2] = sa0; fr[3] = sa1; }
            else         { fr[0] = sc0; fr[1] = sc1; fr[2] = c0;  fr[3] = c1;  }
            bf16x8 pf = __builtin_bit_cast(bf16x8, fr);
            #pragma unroll
            for (int ct = 0; ct < 8; ct++)
                acc[ct] = __builtin_amdgcn_mfma_f32_32x32x16_bf16(vfB[ct], pf, acc[ct], 0, 0, 0);
            #pragma unroll
            for (int i = 0; i < 8; i++)
                vfB[i] = *(const bf16x8*)(vnp + (size_t)(8 + i) * 512);
        }

        kcur0 = kn0; kcur1 = kn1;
    }

    // ---- split-K combine: ks 3,2,1 hand state to ks 0 (elementwise per lane)
    for (int sIdx = 3; sIdx >= 1; --sIdx) {
        if (ks == sIdx) {
            #pragma unroll
            for (int ct = 0; ct < 8; ct++)
                #pragma unroll
                for (int rr = 0; rr < 4; rr++) {
                    float4 v4 = {acc[ct][rr*4+0], acc[ct][rr*4+1], acc[ct][rr*4+2], acc[ct][rr*4+3]};
                    *(float4*)&cacc[lane][ct * 16 + rr * 4] = v4;
                }
            cml[lane][0] = mrun; cml[lane][1] = lrun;
        }
        __syncthreads();
        if (ks == 0) {
            float mo = cml[lane][0];
            float lo = cml[lane][1];
            float mn = fmaxf(mrun, mo);
            float e0 = exp2fast(mrun - mn);
            float e1 = exp2fast(mo - mn);
            mrun = mn;
            lrun = lrun * e0 + lo * e1;
            #pragma unroll
            for (int ct = 0; ct < 8; ct++)
                #pragma unroll
                for (int r = 0; r < 16; r++)
                    acc[ct][r] = acc[ct][r] * e0 + cacc[lane][ct * 16 + r] * e1;
        }
        __syncthreads();
    }

    if (ks == 0) {
        float inv = 1.0f / lrun;
        #pragma unroll
        for (int ct = 0; ct < 8; ct++)
            #pragma unroll
            for (int r = 0; r < 16; r++) {
                int c = ct * 32 + (r & 3) + 8 * (r >> 2) + 4 * hi;
                att[((size_t)b * CC + c) * NP + qt * 32 + q] = acc[ct][r] * inv;
            }
    }
}

// ---------------------------------------------------------------------------
// K4: bilinear x2 upsample (half-pixel, edge clamp) + gamma * up + x, x4 vec
// ---------------------------------------------------------------------------
__global__ __launch_bounds__(256) void upsample_kernel(const float* __restrict__ att,
                                                       const float* __restrict__ x,
                                                       const float* __restrict__ gamma,
                                                       float* __restrict__ out) {
    int tid = blockIdx.x * 256 + threadIdx.x;    // B*C*H*W/4 threads
    int w4 = (tid & 31) * 4;
    int h  = (tid >> 5) & 127;
    int bc = tid >> 12;
    float g = gamma[0];

    float sh = 0.5f * h - 0.25f;
    float fhf = floorf(sh);
    float th = sh - fhf;
    int ih = (int)fhf;
    int ih0 = ih < 0 ? 0 : ih;
    int ih1 = ih + 1 > 63 ? 63 : ih + 1;
    const float* a0r = att + (size_t)bc * NP + ih0 * 64;
    const float* a1r = att + (size_t)bc * NP + ih1 * 64;

    float4 xin = *(const float4*)(x + (size_t)bc * (HH * WW) + h * WW + w4);
    float xv[4] = {xin.x, xin.y, xin.z, xin.w};
    float ov[4];
    #pragma unroll
    for (int k = 0; k < 4; k++) {
        int w = w4 + k;
        float sw = 0.5f * w - 0.25f;
        float fwf = floorf(sw);
        float tw = sw - fwf;
        int iw = (int)fwf;
        int iw0 = iw < 0 ? 0 : iw;
        int iw1 = iw + 1 > 63 ? 63 : iw + 1;
        float v00 = a0r[iw0], v01 = a0r[iw1];
        float v10 = a1r[iw0], v11 = a1r[iw1];
        float top = v00 + tw * (v01 - v00);
        float bot = v10 + tw * (v11 - v10);
        float up  = top + th * (bot - top);
        ov[k] = g * up + xv[k];
    }
    float4 o4 = {ov[0], ov[1], ov[2], ov[3]};
    *(float4*)(out + (size_t)bc * (HH * WW) + h * WW + w4) = o4;
}

// ---------------------------------------------------------------------------
extern "C" void kernel_launch(void* const* d_in, const int* in_sizes, int n_in,
                              void* d_out, int out_size, void* d_ws, size_t ws_size,
                              hipStream_t stream) {
    (void)in_sizes; (void)n_in; (void)out_size; (void)ws_size;
    const float* x     = (const float*)d_in[0];
    const float* wq    = (const float*)d_in[1];
    const float* bq    = (const float*)d_in[2];
    const float* wk    = (const float*)d_in[3];
    const float* bk    = (const float*)d_in[4];
    const float* wv    = (const float*)d_in[5];
    const float* bv    = (const float*)d_in[6];
    const float* gamma = (const float*)d_in[7];
    float* out = (float*)d_out;

    unsigned short* xfrag = (unsigned short*)d_ws;             // 4,194,304 u16 (8 MB)
    unsigned short* wfrag = xfrag + 4194304;                   // 81,920 u16 (pad to 131,072)
    unsigned short* qarr  = wfrag + 131072;                    // 524,288 u16 (1 MB)
    unsigned short* karr  = qarr + 524288;                     // 524,288 u16 (1 MB)
    unsigned short* varr  = karr + 524288;                     // 4,194,304 u16 (8 MB)
    float*          att   = (float*)(varr + 4194304);          // 4,194,304 f32 (16 MB)

    prep_kernel<<<2088, 256, 0, stream>>>(x, wq, wk, wv, xfrag, wfrag);
    projm_kernel<<<2560, 128, 0, stream>>>(xfrag, wfrag, bq, bk, bv, qarr, karr, varr);
    flash32_kernel<<<512, 256, 0, stream>>>(qarr, karr, varr, att);
    upsample_kernel<<<16384, 256, 0, stream>>>(att, x, gamma, out);
}

// Round 17
// 120.100 us; speedup vs baseline: 1.0290x; 1.0290x over previous
//
#include <hip/hip_runtime.h>

// Sizes (fixed by the problem)
#define BB 4
#define CC 256
#define HH 128
#define WW 128
#define HP 64          // pooled H, W
#define NP 4096        // HP*HP tokens per batch

#define L2E 1.4426950408889634f

typedef __attribute__((ext_vector_type(4)))  float f32x4;
typedef __attribute__((ext_vector_type(16))) float f32x16;
typedef __attribute__((ext_vector_type(8)))  short bf16x8;       // 8 bf16 in 4 VGPRs
typedef __attribute__((ext_vector_type(4)))  unsigned int u32x4;
typedef __attribute__((ext_vector_type(2)))  unsigned int u32x2;
typedef __attribute__((ext_vector_type(2)))  __bf16 bf16x2_t;

// 2^x via v_exp_f32 (native). NOT __exp2f: that name collides with glibc macros.
static __device__ __forceinline__ float exp2fast(float x) {
    return __builtin_amdgcn_exp2f(x);
}

// float -> bf16 bits, round-to-nearest-even bit-trick (used on proj/pool paths).
static __device__ __forceinline__ unsigned short f2bf(float f) {
    unsigned int u = __float_as_uint(f);
    u = (u + 0x7FFFu + ((u >> 16) & 1u)) >> 16;
    return (unsigned short)u;
}
// flash P-pack: compiler-fused v_cvt_pk_bf16_f32 (plain casts — absmax-neutral, R15).
static __device__ __forceinline__ unsigned int pk2(float a, float b) {
    bf16x2_t v = {(__bf16)a, (__bf16)b};
    return __builtin_bit_cast(unsigned int, v);
}
// lane<->lane+32 exchange on the VALU pipe (T12). BUILTIN, not inline asm:
// the R9/R10 asm "+v" aliasing corrupted results; the builtin returns a proper
// SSA pair. swap(A,B) -> (r.x, r.y) = ([A.lo;B.lo], [A.hi;B.hi]):
//   r.x: lanes0-31 = A[l], lanes32-63 = B[l-32]
//   r.y: lanes0-31 = A[l+32], lanes32-63 = B[l]
static __device__ __forceinline__ u32x2 plswap(unsigned int a, unsigned int b) {
    return __builtin_amdgcn_permlane32_swap(a, b, false, false);
}

// ---------------------------------------------------------------------------
// Fragment-ordered layouts (bf16):
//   xfrag[b][nt(128)][ks(16)][lane(64)][e(8)] : B-frag, X[c][n]
//   wfrag[ot(10)][ks(16)][lane(64)][e(8)]     : A-frag, W[o][c] (Q rows xL2E)
//   Q2[qtile(128)][f(2)][q(32)][hi(2)][e(8)]
//   K2[kchunk(128)][f(2)][k(32)][hi(2)][e(8)]
//   V2[kc(128)][w2(2)][ctg(8)][q(32)][hi(2)][e(8)]
// mfma_32x32x16_bf16 (m74/m101): A row=lane&31, k=(lane>>5)*8+e; B col=lane&31,
// same k; D col=lane&31, row=(r&3)+8*(r>>2)+4*(lane>>5).
// ---------------------------------------------------------------------------

// ---------------------------------------------------------------------------
// K1: fused 2x2 avg-pool + bf16 B-fragment layout, PLUS (blocks >= 2048)
// the one-time W -> A-fragment reorder (merged to save a launch).
// ---------------------------------------------------------------------------
__global__ __launch_bounds__(256) void prep_kernel(const float* __restrict__ x,
                                                   const float* __restrict__ wq,
                                                   const float* __restrict__ wk,
                                                   const float* __restrict__ wv,
                                                   unsigned short* __restrict__ xfrag,
                                                   unsigned short* __restrict__ wfrag) {
    if (blockIdx.x < 2048) {
        int tid  = blockIdx.x * 256 + threadIdx.x;   // 4*128*16*64 = 524,288 threads
        int lane = tid & 63;
        int ks   = (tid >> 6) & 15;
        int nt   = (tid >> 10) & 127;
        int b    = tid >> 17;

        int n  = nt * 32 + (lane & 31);
        int c0 = ks * 16 + (lane >> 5) * 8;
        int hp = n >> 6, wp = n & 63;

        const float* xb = x + (size_t)b * CC * (HH * WW) + (2 * hp) * WW + 2 * wp;
        unsigned short r[8];
        #pragma unroll
        for (int e = 0; e < 8; e++) {
            const float* src = xb + (size_t)(c0 + e) * (HH * WW);
            float2 a = *(const float2*)(src);
            float2 d = *(const float2*)(src + WW);
            r[e] = f2bf(0.25f * (a.x + a.y + d.x + d.y));
        }
        ushort4 lo = (ushort4){r[0], r[1], r[2], r[3]};
        ushort4 hi = (ushort4){r[4], r[5], r[6], r[7]};
        *(ushort4*)(xfrag + (size_t)tid * 8)     = lo;
        *(ushort4*)(xfrag + (size_t)tid * 8 + 4) = hi;
    } else {
        int tid  = (blockIdx.x - 2048) * 256 + threadIdx.x;   // 10*16*64 = 10,240
        if (tid >= 10240) return;
        int lane = tid & 63;
        int ks   = (tid >> 6) & 15;
        int ot   = tid >> 10;

        int o = ot * 32 + (lane & 31);
        int c = ks * 16 + (lane >> 5) * 8;
        const float* wrow;
        float scale = 1.0f;
        if (o < 32)      { wrow = wq + (size_t)o * CC;        scale = L2E; }
        else if (o < 64) { wrow = wk + (size_t)(o - 32) * CC; }
        else             { wrow = wv + (size_t)(o - 64) * CC; }
        float4 w0 = *(const float4*)(wrow + c);
        float4 w1 = *(const float4*)(wrow + c + 4);
        ushort4 lo = {f2bf(w0.x * scale), f2bf(w0.y * scale), f2bf(w0.z * scale), f2bf(w0.w * scale)};
        ushort4 hi = {f2bf(w1.x * scale), f2bf(w1.y * scale), f2bf(w1.z * scale), f2bf(w1.w * scale)};
        *(ushort4*)(wfrag + (size_t)tid * 8)     = lo;
        *(ushort4*)(wfrag + (size_t)tid * 8 + 4) = hi;
    }
}

// ---------------------------------------------------------------------------
// K2: MFMA projection GEMM. Block = 2 waves; wave computes one 32o x 32n
// tile over K=256 (16 MFMA). All operand loads are contiguous 1KB/wave.
// Epilogue adds bias and scatter-stores into Q2/K2/V2 fragment layouts.
// ---------------------------------------------------------------------------
__global__ __launch_bounds__(128) void projm_kernel(const unsigned short* __restrict__ xfrag,
                                                    const unsigned short* __restrict__ wfrag,
                                                    const float* __restrict__ bq,
                                                    const float* __restrict__ bk,
                                                    const float* __restrict__ bv,
                                                    unsigned short* __restrict__ qarr,
                                                    unsigned short* __restrict__ karr,
                                                    unsigned short* __restrict__ varr) {
    int j    = blockIdx.x;            // 4b * 128nt * 5og = 2560
    int og   = j % 5;
    int nt   = (j / 5) & 127;
    int b    = j / 640;
    int lane = threadIdx.x & 63;
    int ot   = og * 2 + (threadIdx.x >> 6);   // 0..9

    const unsigned short* abase = wfrag + ((size_t)ot * 16 * 64 + lane) * 8;
    const unsigned short* bbase = xfrag + (((size_t)(b * 128 + nt) * 16) * 64 + lane) * 8;

    f32x16 acc;
    #pragma unroll
    for (int r = 0; r < 16; r++) acc[r] = 0.f;

    #pragma unroll
    for (int ks = 0; ks < 16; ks++) {
        bf16x8 af = *(const bf16x8*)(abase + (size_t)ks * 512);
        bf16x8 bf = *(const bf16x8*)(bbase + (size_t)ks * 512);
        acc = __builtin_amdgcn_mfma_f32_32x32x16_bf16(af, bf, acc, 0, 0, 0);
    }

    int l31 = lane & 31;
    int hi2 = lane >> 5;

    if (ot == 0) {
        unsigned short* qb = qarr + (size_t)b * (NP * 32);
        #pragma unroll
        for (int r = 0; r < 16; r++) {
            int o = (r & 3) + 8 * (r >> 2) + 4 * hi2;
            float v = acc[r] + bq[o] * L2E;
            size_t idx = (((size_t)nt * 2 + (o >> 4)) * 32 + l31) * 16 + ((o >> 3) & 1) * 8 + (o & 7);
            qb[idx] = f2bf(v);
        }
    } else if (ot == 1) {
        unsigned short* kb = karr + (size_t)b * (NP * 32);
        #pragma unroll
        for (int r = 0; r < 16; r++) {
            int o = (r & 3) + 8 * (r >> 2) + 4 * hi2;
            float v = acc[r] + bk[o];
            size_t idx = (((size_t)nt * 2 + (o >> 4)) * 32 + l31) * 16 + ((o >> 3) & 1) * 8 + (o & 7);
            kb[idx] = f2bf(v);
        }
    } else {
        unsigned short* vb = varr + (size_t)b * (CC * NP);
        int kc = nt, w2 = (l31 >> 4) & 1, hiv = (l31 >> 3) & 1, ev = l31 & 7;
        size_t base = (((size_t)kc * 2 + w2) * 8) * 32 * 16 + hiv * 8 + ev;
        #pragma unroll
        for (int r = 0; r < 16; r++) {
            int c = (ot - 2) * 32 + (r & 3) + 8 * (r >> 2) + 4 * hi2;
            float v = acc[r] + bv[c];
            size_t idx = base + ((size_t)(c >> 5) * 32 + (c & 31)) * 16;
            vb[idx] = f2bf(v);
        }
    }
}

// ---------------------------------------------------------------------------
// K3: swapped-operand 32x32 MFMA flash attention, FULL-CHANNEL waves,
// depth-2 V pipeline (R16) + ALL lane<->lane+32 exchanges via
// permlane32_swap builtin (VALU, ~6cy) instead of ds_bpermute (~110cy LDS
// round-trip). 10 bpermutes/iter sat on the serial softmax critical path —
// the invariant ~800cy/iter stall across R12-R16.
// ---------------------------------------------------------------------------
__global__ __launch_bounds__(256, 2) void flash32_kernel(const unsigned short* __restrict__ qarr,
                                                         const unsigned short* __restrict__ karr,
                                                         const unsigned short* __restrict__ varr,
                                                         float* __restrict__ att) {
    __shared__ float cacc[64][140];    // combine: 128 f32/lane (140: avoids 16-way conflicts)
    __shared__ float cml[64][2];       // combine: m, l per lane
    int t    = threadIdx.x;
    int lane = t & 63;
    int ks   = t >> 6;                 // 0..3 key quarter
    int j    = blockIdx.x;
    int b    = j & 3;                  // batch -> XCD pinning
    int qt   = j >> 2;                 // 0..127 q-tile (32 rows)

    const unsigned short* qb2 = qarr + (size_t)b * (NP * 32);
    const unsigned short* kb2 = karr + (size_t)b * (NP * 32);
    const unsigned short* vb2 = varr + (size_t)b * (CC * NP);

    int q  = lane & 31;
    int hi = lane >> 5;
    int lq16 = (q * 2 + hi) * 8;       // lane's 16B slot within a 1KB fragment block

    bf16x8 qf0 = *(const bf16x8*)(qb2 + (size_t)(qt * 2 + 0) * 512 + lq16);
    bf16x8 qf1 = *(const bf16x8*)(qb2 + (size_t)(qt * 2 + 1) * 512 + lq16);

    f32x16 acc[8];
    #pragma unroll
    for (int ct = 0; ct < 8; ct++)
        #pragma unroll
        for (int r = 0; r < 16; r++) acc[ct][r] = 0.f;
    float mrun = -3.0e38f, lrun = 0.f;

    const f32x16 z16 = {0.f,0.f,0.f,0.f,0.f,0.f,0.f,0.f,0.f,0.f,0.f,0.f,0.f,0.f,0.f,0.f};

    // ---- prologue: K + both V halves for first chunk
    int kc0 = ks * 32;
    const unsigned short* kcp0 = kb2 + (size_t)kc0 * 1024 + lq16;
    bf16x8 kcur0 = *(const bf16x8*)(kcp0);
    bf16x8 kcur1 = *(const bf16x8*)(kcp0 + 512);
    bf16x8 vfA[8], vfB[8];
    {
        const unsigned short* vcp0 = vb2 + ((size_t)kc0 * 16) * 512 + lq16;
        #pragma unroll
        for (int i = 0; i < 8; i++) vfA[i] = *(const bf16x8*)(vcp0 + (size_t)i * 512);
        #pragma unroll
        for (int i = 0; i < 8; i++) vfB[i] = *(const bf16x8*)(vcp0 + (size_t)(8 + i) * 512);
    }

    for (int kci = 0; kci < 32; ++kci) {
        int kcidx = kc0 + kci;
        int nid = (kci < 31) ? (kcidx + 1) : kcidx;   // clamp: last iter reloads

        // ---- K loads for NEXT chunk (consumed next iteration)
        const unsigned short* kn = kb2 + (size_t)nid * 1024 + lq16;
        bf16x8 kn0 = *(const bf16x8*)(kn);
        bf16x8 kn1 = *(const bf16x8*)(kn + 512);

        // ---- QK^T swapped (operands loaded one iteration ago)
        f32x16 s = __builtin_amdgcn_mfma_f32_32x32x16_bf16(kcur0, qf0, z16, 0, 0, 0);
        s = __builtin_amdgcn_mfma_f32_32x32x16_bf16(kcur1, qf1, s, 0, 0, 0);

        // ---- in-lane max over 16 keys + 1 cross-half swap (permlane, VALU)
        float m01 = fmaxf(s[0], s[1]),   m23 = fmaxf(s[2], s[3]);
        float m45 = fmaxf(s[4], s[5]),   m67 = fmaxf(s[6], s[7]);
        float m89 = fmaxf(s[8], s[9]),   mab = fmaxf(s[10], s[11]);
        float mcd = fmaxf(s[12], s[13]), mef = fmaxf(s[14], s[15]);
        float mx = fmaxf(fmaxf(fmaxf(m01, m23), fmaxf(m45, m67)),
                         fmaxf(fmaxf(m89, mab), fmaxf(mcd, mef)));
        {
            u32x2 mr = plswap(__float_as_uint(mx), __float_as_uint(mx));
            mx = fmaxf(__uint_as_float(mr.x), __uint_as_float(mr.y));
        }

        // ---- defer-max (T13, log2 domain)
        if (!__all(mx - mrun <= 11.5f)) {
            float mn = fmaxf(mrun, mx);
            float sc = exp2fast(mrun - mn);
            mrun = mn;
            lrun *= sc;
            #pragma unroll
            for (int ct = 0; ct < 8; ct++)
                #pragma unroll
                for (int r = 0; r < 16; r++) acc[ct][r] *= sc;
        }

        // ---- P = exp2(S^T - m): cvt_pk pack + depth-4 tree sum
        unsigned int pkr[8];
        float ps[8];
        #pragma unroll
        for (int r2 = 0; r2 < 8; r2++) {
            float p0 = exp2fast(s[2 * r2]     - mrun);
            float p1 = exp2fast(s[2 * r2 + 1] - mrun);
            ps[r2] = p0 + p1;
            pkr[r2] = pk2(p0, p1);
        }
        float s01 = ps[0] + ps[1], s23 = ps[2] + ps[3];
        float s45 = ps[4] + ps[5], s67 = ps[6] + ps[7];
        float ss = (s01 + s23) + (s45 + s67);
        {
            u32x2 sr = plswap(__float_as_uint(ss), __float_as_uint(ss));
            ss = __uint_as_float(sr.x) + __uint_as_float(sr.y);
        }
        lrun += ss;

        const unsigned short* vnp = vb2 + ((size_t)nid * 16) * 512 + lq16;

        // ---- PV half 0 (vfA), P B-frag via 2 permlane swaps, then refill vfA
        {
            u32x2 r0 = plswap(pkr[0], pkr[2]);
            u32x2 r1 = plswap(pkr[1], pkr[3]);
            u32x4 fr; fr[0] = r0.x; fr[1] = r1.x; fr[2] = r0.y; fr[3] = r1.y;
            bf16x8 pf = __builtin_bit_cast(bf16x8, fr);
            #pragma unroll
            for (int ct = 0; ct < 8; ct++)
                acc[ct] = __builtin_amdgcn_mfma_f32_32x32x16_bf16(vfA[ct], pf, acc[ct], 0, 0, 0);
            #pragma unroll
            for (int i = 0; i < 8; i++)
                vfA[i] = *(const bf16x8*)(vnp + (size_t)i * 512);
        }

        // ---- PV half 1 (vfB), then refill vfB
        {
            u32x2 r0 = plswap(pkr[4], pkr[6]);
            u32x2 r1 = plswap(pkr[5], pkr[7]);
            u32x4 fr; fr[0] = r0.x; fr[1] = r1.x; fr[2] = r0.y; fr[3] = r1.y;
            bf16x8 pf = __builtin_bit_cast(bf16x8, fr);
            #pragma unroll
            for (int ct = 0; ct < 8; ct++)
                acc[ct] = __builtin_amdgcn_mfma_f32_32x32x16_bf16(vfB[ct], pf, acc[ct], 0, 0, 0);
            #pragma unroll
            for (int i = 0; i < 8; i++)
                vfB[i] = *(const bf16x8*)(vnp + (size_t)(8 + i) * 512);
        }

        kcur0 = kn0; kcur1 = kn1;
    }

    // ---- split-K combine: ks 3,2,1 hand state to ks 0 (elementwise per lane)
    for (int sIdx = 3; sIdx >= 1; --sIdx) {
        if (ks == sIdx) {
            #pragma unroll
            for (int ct = 0; ct < 8; ct++)
                #pragma unroll
                for (int rr = 0; rr < 4; rr++) {
                    float4 v4 = {acc[ct][rr*4+0], acc[ct][rr*4+1], acc[ct][rr*4+2], acc[ct][rr*4+3]};
                    *(float4*)&cacc[lane][ct * 16 + rr * 4] = v4;
                }
            cml[lane][0] = mrun; cml[lane][1] = lrun;
        }
        __syncthreads();
        if (ks == 0) {
            float mo = cml[lane][0];
            float lo = cml[lane][1];
            float mn = fmaxf(mrun, mo);
            float e0 = exp2fast(mrun - mn);
            float e1 = exp2fast(mo - mn);
            mrun = mn;
            lrun = lrun * e0 + lo * e1;
            #pragma unroll
            for (int ct = 0; ct < 8; ct++)
                #pragma unroll
                for (int r = 0; r < 16; r++)
                    acc[ct][r] = acc[ct][r] * e0 + cacc[lane][ct * 16 + r] * e1;
        }
        __syncthreads();
    }

    if (ks == 0) {
        float inv = 1.0f / lrun;
        #pragma unroll
        for (int ct = 0; ct < 8; ct++)
            #pragma unroll
            for (int r = 0; r < 16; r++) {
                int c = ct * 32 + (r & 3) + 8 * (r >> 2) + 4 * hi;
                att[((size_t)b * CC + c) * NP + qt * 32 + q] = acc[ct][r] * inv;
            }
    }
}

// ---------------------------------------------------------------------------
// K4: bilinear x2 upsample (half-pixel, edge clamp) + gamma * up + x, x4 vec
// ---------------------------------------------------------------------------
__global__ __launch_bounds__(256) void upsample_kernel(const float* __restrict__ att,
                                                       const float* __restrict__ x,
                                                       const float* __restrict__ gamma,
                                                       float* __restrict__ out) {
    int tid = blockIdx.x * 256 + threadIdx.x;    // B*C*H*W/4 threads
    int w4 = (tid & 31) * 4;
    int h  = (tid >> 5) & 127;
    int bc = tid >> 12;
    float g = gamma[0];

    float sh = 0.5f * h - 0.25f;
    float fhf = floorf(sh);
    float th = sh - fhf;
    int ih = (int)fhf;
    int ih0 = ih < 0 ? 0 : ih;
    int ih1 = ih + 1 > 63 ? 63 : ih + 1;
    const float* a0r = att + (size_t)bc * NP + ih0 * 64;
    const float* a1r = att + (size_t)bc * NP + ih1 * 64;

    float4 xin = *(const float4*)(x + (size_t)bc * (HH * WW) + h * WW + w4);
    float xv[4] = {xin.x, xin.y, xin.z, xin.w};
    float ov[4];
    #pragma unroll
    for (int k = 0; k < 4; k++) {
        int w = w4 + k;
        float sw = 0.5f * w - 0.25f;
        float fwf = floorf(sw);
        float tw = sw - fwf;
        int iw = (int)fwf;
        int iw0 = iw < 0 ? 0 : iw;
        int iw1 = iw + 1 > 63 ? 63 : iw + 1;
        float v00 = a0r[iw0], v01 = a0r[iw1];
        float v10 = a1r[iw0], v11 = a1r[iw1];
        float top = v00 + tw * (v01 - v00);
        float bot = v10 + tw * (v11 - v10);
        float up  = top + th * (bot - top);
        ov[k] = g * up + xv[k];
    }
    float4 o4 = {ov[0], ov[1], ov[2], ov[3]};
    *(float4*)(out + (size_t)bc * (HH * WW) + h * WW + w4) = o4;
}

// ---------------------------------------------------------------------------
extern "C" void kernel_launch(void* const* d_in, const int* in_sizes, int n_in,
                              void* d_out, int out_size, void* d_ws, size_t ws_size,
                              hipStream_t stream) {
    (void)in_sizes; (void)n_in; (void)out_size; (void)ws_size;
    const float* x     = (const float*)d_in[0];
    const float* wq    = (const float*)d_in[1];
    const float* bq    = (const float*)d_in[2];
    const float* wk    = (const float*)d_in[3];
    const float* bk    = (const float*)d_in[4];
    const float* wv    = (const float*)d_in[5];
    const float* bv    = (const float*)d_in[6];
    const float* gamma = (const float*)d_in[7];
    float* out = (float*)d_out;

    unsigned short* xfrag = (unsigned short*)d_ws;             // 4,194,304 u16 (8 MB)
    unsigned short* wfrag = xfrag + 4194304;                   // 81,920 u16 (pad to 131,072)
    unsigned short* qarr  = wfrag + 131072;                    // 524,288 u16 (1 MB)
    unsigned short* karr  = qarr + 524288;                     // 524,288 u16 (1 MB)
    unsigned short* varr  = karr + 524288;                     // 4,194,304 u16 (8 MB)
    float*          att   = (float*)(varr + 4194304);          // 4,194,304 f32 (16 MB)

    prep_kernel<<<2088, 256, 0, stream>>>(x, wq, wk, wv, xfrag, wfrag);
    projm_kernel<<<2560, 128, 0, stream>>>(xfrag, wfrag, bq, bk, bv, qarr, karr, varr);
    flash32_kernel<<<512, 256, 0, stream>>>(qarr, karr, varr, att);
    upsample_kernel<<<16384, 256, 0, stream>>>(att, x, gamma, out);
}

// Round 18
// 119.197 us; speedup vs baseline: 1.0368x; 1.0076x over previous
//
#include <hip/hip_runtime.h>

// Sizes (fixed by the problem)
#define BB 4
#define CC 256
#define HH 128
#define WW 128
#define HP 64          // pooled H, W
#define NP 4096        // HP*HP tokens per batch

#define L2E 1.4426950408889634f

typedef __attribute__((ext_vector_type(4)))  float f32x4;
typedef __attribute__((ext_vector_type(16))) float f32x16;
typedef __attribute__((ext_vector_type(8)))  short bf16x8;       // 8 bf16 in 4 VGPRs
typedef __attribute__((ext_vector_type(4)))  unsigned int u32x4;
typedef __attribute__((ext_vector_type(2)))  unsigned int u32x2;
typedef __attribute__((ext_vector_type(2)))  __bf16 bf16x2_t;

// 2^x via v_exp_f32 (native). NOT __exp2f: that name collides with glibc macros.
static __device__ __forceinline__ float exp2fast(float x) {
    return __builtin_amdgcn_exp2f(x);
}

// float -> bf16 bits, round-to-nearest-even bit-trick (used on proj/pool paths).
static __device__ __forceinline__ unsigned short f2bf(float f) {
    unsigned int u = __float_as_uint(f);
    u = (u + 0x7FFFu + ((u >> 16) & 1u)) >> 16;
    return (unsigned short)u;
}
// flash P-pack: compiler-fused v_cvt_pk_bf16_f32 (plain casts — absmax-neutral, R15).
static __device__ __forceinline__ unsigned int pk2(float a, float b) {
    bf16x2_t v = {(__bf16)a, (__bf16)b};
    return __builtin_bit_cast(unsigned int, v);
}
// lane<->lane+32 exchange on the VALU pipe (T12). BUILTIN (R17-verified):
// swap(A,B) -> (r.x, r.y) = ([A.lo;B.lo], [A.hi;B.hi]).
static __device__ __forceinline__ u32x2 plswap(unsigned int a, unsigned int b) {
    return __builtin_amdgcn_permlane32_swap(a, b, false, false);
}

// ---------------------------------------------------------------------------
// Fragment-ordered layouts (bf16):
//   xfrag[b][nt(128)][ks(16)][lane(64)][e(8)] : B-frag, X[c][n]
//   wfrag[ot(10)][ks(16)][lane(64)][e(8)]     : A-frag, W[o][c] (Q rows xL2E)
//   Q2[qtile(128)][f(2)][q(32)][hi(2)][e(8)]
//   K2[kchunk(128)][f(2)][k(32)][hi(2)][e(8)]
//   V2[kc(128)][w2(2)][ctg(8)][q(32)][hi(2)][e(8)]
// mfma_32x32x16_bf16 (m74/m101): A row=lane&31, k=(lane>>5)*8+e; B col=lane&31,
// same k; D col=lane&31, row=(r&3)+8*(r>>2)+4*(lane>>5).
// ---------------------------------------------------------------------------

// ---------------------------------------------------------------------------
// K1: fused 2x2 avg-pool + bf16 B-fragment layout, PLUS (blocks >= 2048)
// the one-time W -> A-fragment reorder (merged to save a launch).
// ---------------------------------------------------------------------------
__global__ __launch_bounds__(256) void prep_kernel(const float* __restrict__ x,
                                                   const float* __restrict__ wq,
                                                   const float* __restrict__ wk,
                                                   const float* __restrict__ wv,
                                                   unsigned short* __restrict__ xfrag,
                                                   unsigned short* __restrict__ wfrag) {
    if (blockIdx.x < 2048) {
        int tid  = blockIdx.x * 256 + threadIdx.x;   // 4*128*16*64 = 524,288 threads
        int lane = tid & 63;
        int ks   = (tid >> 6) & 15;
        int nt   = (tid >> 10) & 127;
        int b    = tid >> 17;

        int n  = nt * 32 + (lane & 31);
        int c0 = ks * 16 + (lane >> 5) * 8;
        int hp = n >> 6, wp = n & 63;

        const float* xb = x + (size_t)b * CC * (HH * WW) + (2 * hp) * WW + 2 * wp;
        unsigned short r[8];
        #pragma unroll
        for (int e = 0; e < 8; e++) {
            const float* src = xb + (size_t)(c0 + e) * (HH * WW);
            float2 a = *(const float2*)(src);
            float2 d = *(const float2*)(src + WW);
            r[e] = f2bf(0.25f * (a.x + a.y + d.x + d.y));
        }
        ushort4 lo = (ushort4){r[0], r[1], r[2], r[3]};
        ushort4 hi = (ushort4){r[4], r[5], r[6], r[7]};
        *(ushort4*)(xfrag + (size_t)tid * 8)     = lo;
        *(ushort4*)(xfrag + (size_t)tid * 8 + 4) = hi;
    } else {
        int tid  = (blockIdx.x - 2048) * 256 + threadIdx.x;   // 10*16*64 = 10,240
        if (tid >= 10240) return;
        int lane = tid & 63;
        int ks   = (tid >> 6) & 15;
        int ot   = tid >> 10;

        int o = ot * 32 + (lane & 31);
        int c = ks * 16 + (lane >> 5) * 8;
        const float* wrow;
        float scale = 1.0f;
        if (o < 32)      { wrow = wq + (size_t)o * CC;        scale = L2E; }
        else if (o < 64) { wrow = wk + (size_t)(o - 32) * CC; }
        else             { wrow = wv + (size_t)(o - 64) * CC; }
        float4 w0 = *(const float4*)(wrow + c);
        float4 w1 = *(const float4*)(wrow + c + 4);
        ushort4 lo = {f2bf(w0.x * scale), f2bf(w0.y * scale), f2bf(w0.z * scale), f2bf(w0.w * scale)};
        ushort4 hi = {f2bf(w1.x * scale), f2bf(w1.y * scale), f2bf(w1.z * scale), f2bf(w1.w * scale)};
        *(ushort4*)(wfrag + (size_t)tid * 8)     = lo;
        *(ushort4*)(wfrag + (size_t)tid * 8 + 4) = hi;
    }
}

// ---------------------------------------------------------------------------
// K2: MFMA projection GEMM. Block = 2 waves; wave computes one 32o x 32n
// tile over K=256 (16 MFMA). All operand loads are contiguous 1KB/wave.
// Epilogue adds bias and scatter-stores into Q2/K2/V2 fragment layouts.
// ---------------------------------------------------------------------------
__global__ __launch_bounds__(128) void projm_kernel(const unsigned short* __restrict__ xfrag,
                                                    const unsigned short* __restrict__ wfrag,
                                                    const float* __restrict__ bq,
                                                    const float* __restrict__ bk,
                                                    const float* __restrict__ bv,
                                                    unsigned short* __restrict__ qarr,
                                                    unsigned short* __restrict__ karr,
                                                    unsigned short* __restrict__ varr) {
    int j    = blockIdx.x;            // 4b * 128nt * 5og = 2560
    int og   = j % 5;
    int nt   = (j / 5) & 127;
    int b    = j / 640;
    int lane = threadIdx.x & 63;
    int ot   = og * 2 + (threadIdx.x >> 6);   // 0..9

    const unsigned short* abase = wfrag + ((size_t)ot * 16 * 64 + lane) * 8;
    const unsigned short* bbase = xfrag + (((size_t)(b * 128 + nt) * 16) * 64 + lane) * 8;

    f32x16 acc;
    #pragma unroll
    for (int r = 0; r < 16; r++) acc[r] = 0.f;

    #pragma unroll
    for (int ks = 0; ks < 16; ks++) {
        bf16x8 af = *(const bf16x8*)(abase + (size_t)ks * 512);
        bf16x8 bf = *(const bf16x8*)(bbase + (size_t)ks * 512);
        acc = __builtin_amdgcn_mfma_f32_32x32x16_bf16(af, bf, acc, 0, 0, 0);
    }

    int l31 = lane & 31;
    int hi2 = lane >> 5;

    if (ot == 0) {
        unsigned short* qb = qarr + (size_t)b * (NP * 32);
        #pragma unroll
        for (int r = 0; r < 16; r++) {
            int o = (r & 3) + 8 * (r >> 2) + 4 * hi2;
            float v = acc[r] + bq[o] * L2E;
            size_t idx = (((size_t)nt * 2 + (o >> 4)) * 32 + l31) * 16 + ((o >> 3) & 1) * 8 + (o & 7);
            qb[idx] = f2bf(v);
        }
    } else if (ot == 1) {
        unsigned short* kb = karr + (size_t)b * (NP * 32);
        #pragma unroll
        for (int r = 0; r < 16; r++) {
            int o = (r & 3) + 8 * (r >> 2) + 4 * hi2;
            float v = acc[r] + bk[o];
            size_t idx = (((size_t)nt * 2 + (o >> 4)) * 32 + l31) * 16 + ((o >> 3) & 1) * 8 + (o & 7);
            kb[idx] = f2bf(v);
        }
    } else {
        unsigned short* vb = varr + (size_t)b * (CC * NP);
        int kc = nt, w2 = (l31 >> 4) & 1, hiv = (l31 >> 3) & 1, ev = l31 & 7;
        size_t base = (((size_t)kc * 2 + w2) * 8) * 32 * 16 + hiv * 8 + ev;
        #pragma unroll
        for (int r = 0; r < 16; r++) {
            int c = (ot - 2) * 32 + (r & 3) + 8 * (r >> 2) + 4 * hi2;
            float v = acc[r] + bv[c];
            size_t idx = base + ((size_t)(c >> 5) * 32 + (c & 31)) * 16;
            vb[idx] = f2bf(v);
        }
    }
}

// ---------------------------------------------------------------------------
// K3: swapped-operand 32x32 MFMA flash attention, 2 Q-TILES x ch-split x
// ks-split. Each V fragment feeds TWO q-tiles -> per-XCD L2 read traffic
// halves (144->72MB; L2-BW was 52% at R17) and MFMA:load doubles. 512-thread
// block = 8 waves: ch = w&1 (128 channels), ks = w>>1 (1024 keys). Softmax
// per tile via permlane+cvt_pk+tree (cheap enough to duplicate — R11's
// blocker, removed). K-next prefetch + V top-of-iter hoist (R14).
// ---------------------------------------------------------------------------
__global__ __launch_bounds__(512, 2) void flash32_kernel(const unsigned short* __restrict__ qarr,
                                                         const unsigned short* __restrict__ karr,
                                                         const unsigned short* __restrict__ varr,
                                                         float* __restrict__ att) {
    __shared__ float cacc[2][64][68];  // combine: per ch-group, 64 f32/lane (one tile at a time)
    __shared__ float cml[2][64][2];    // combine: m, l per lane
    int t    = threadIdx.x;
    int lane = t & 63;
    int w    = t >> 6;                 // 0..7
    int ch   = w & 1;                  // channel half
    int ks   = w >> 1;                 // key quarter
    int j    = blockIdx.x;
    int b    = j & 3;                  // batch -> XCD pinning
    int st   = j >> 2;                 // 0..63 q-supertile (64 rows)
    int qt0  = st * 2, qt1 = qt0 + 1;

    const unsigned short* qb2 = qarr + (size_t)b * (NP * 32);
    const unsigned short* kb2 = karr + (size_t)b * (NP * 32);
    const unsigned short* vb2 = varr + (size_t)b * (CC * NP);

    int q  = lane & 31;
    int hi = lane >> 5;
    int lq16 = (q * 2 + hi) * 8;       // lane's 16B slot within a 1KB fragment block

    bf16x8 qA0 = *(const bf16x8*)(qb2 + (size_t)(qt0 * 2 + 0) * 512 + lq16);
    bf16x8 qA1 = *(const bf16x8*)(qb2 + (size_t)(qt0 * 2 + 1) * 512 + lq16);
    bf16x8 qB0 = *(const bf16x8*)(qb2 + (size_t)(qt1 * 2 + 0) * 512 + lq16);
    bf16x8 qB1 = *(const bf16x8*)(qb2 + (size_t)(qt1 * 2 + 1) * 512 + lq16);

    f32x16 accA[4], accB[4];
    #pragma unroll
    for (int ct = 0; ct < 4; ct++)
        #pragma unroll
        for (int r = 0; r < 16; r++) { accA[ct][r] = 0.f; accB[ct][r] = 0.f; }
    float mrunA = -3.0e38f, lrunA = 0.f;
    float mrunB = -3.0e38f, lrunB = 0.f;

    const f32x16 z16 = {0.f,0.f,0.f,0.f,0.f,0.f,0.f,0.f,0.f,0.f,0.f,0.f,0.f,0.f,0.f,0.f};

    // ---- prologue: K frags for first chunk
    int kc0 = ks * 32;
    const unsigned short* kcp0 = kb2 + (size_t)kc0 * 1024 + lq16;
    bf16x8 kcur0 = *(const bf16x8*)(kcp0);
    bf16x8 kcur1 = *(const bf16x8*)(kcp0 + 512);

    for (int kci = 0; kci < 32; ++kci) {
        int kcidx = kc0 + kci;
        int nid = (kci < 31) ? (kcidx + 1) : kcidx;

        // ---- V frags for THIS chunk, our 128-ch half (consumed after softmax)
        const unsigned short* vcp = vb2 + ((size_t)kcidx * 16 + ch * 4) * 512 + lq16;
        bf16x8 vf[8];
        #pragma unroll
        for (int w2 = 0; w2 < 2; w2++)
            #pragma unroll
            for (int i = 0; i < 4; i++)
                vf[w2 * 4 + i] = *(const bf16x8*)(vcp + (size_t)(w2 * 8 + i) * 512);

        // ---- K loads for NEXT chunk
        const unsigned short* kn = kb2 + (size_t)nid * 1024 + lq16;
        bf16x8 kn0 = *(const bf16x8*)(kn);
        bf16x8 kn1 = *(const bf16x8*)(kn + 512);

        // ---- QK^T swapped, both tiles (K operands shared)
        f32x16 sA = __builtin_amdgcn_mfma_f32_32x32x16_bf16(kcur0, qA0, z16, 0, 0, 0);
        sA = __builtin_amdgcn_mfma_f32_32x32x16_bf16(kcur1, qA1, sA, 0, 0, 0);
        f32x16 sB = __builtin_amdgcn_mfma_f32_32x32x16_bf16(kcur0, qB0, z16, 0, 0, 0);
        sB = __builtin_amdgcn_mfma_f32_32x32x16_bf16(kcur1, qB1, sB, 0, 0, 0);

        // ---- softmax tile A (permlane + defer-max + cvt_pk + tree-sum)
        unsigned int pkrA[8];
        {
            float m01 = fmaxf(sA[0], sA[1]),   m23 = fmaxf(sA[2], sA[3]);
            float m45 = fmaxf(sA[4], sA[5]),   m67 = fmaxf(sA[6], sA[7]);
            float m89 = fmaxf(sA[8], sA[9]),   mab = fmaxf(sA[10], sA[11]);
            float mcd = fmaxf(sA[12], sA[13]), mef = fmaxf(sA[14], sA[15]);
            float mx = fmaxf(fmaxf(fmaxf(m01, m23), fmaxf(m45, m67)),
                             fmaxf(fmaxf(m89, mab), fmaxf(mcd, mef)));
            u32x2 mr = plswap(__float_as_uint(mx), __float_as_uint(mx));
            mx = fmaxf(__uint_as_float(mr.x), __uint_as_float(mr.y));
            if (!__all(mx - mrunA <= 11.5f)) {
                float mn = fmaxf(mrunA, mx);
                float sc = exp2fast(mrunA - mn);
                mrunA = mn;
                lrunA *= sc;
                #pragma unroll
                for (int ct = 0; ct < 4; ct++)
                    #pragma unroll
                    for (int r = 0; r < 16; r++) accA[ct][r] *= sc;
            }
            float ps[8];
            #pragma unroll
            for (int r2 = 0; r2 < 8; r2++) {
                float p0 = exp2fast(sA[2 * r2]     - mrunA);
                float p1 = exp2fast(sA[2 * r2 + 1] - mrunA);
                ps[r2] = p0 + p1;
                pkrA[r2] = pk2(p0, p1);
            }
            float s01 = ps[0] + ps[1], s23 = ps[2] + ps[3];
            float s45 = ps[4] + ps[5], s67 = ps[6] + ps[7];
            float ssum = (s01 + s23) + (s45 + s67);
            u32x2 sr = plswap(__float_as_uint(ssum), __float_as_uint(ssum));
            lrunA += __uint_as_float(sr.x) + __uint_as_float(sr.y);
        }

        // ---- softmax tile B
        unsigned int pkrB[8];
        {
            float m01 = fmaxf(sB[0], sB[1]),   m23 = fmaxf(sB[2], sB[3]);
            float m45 = fmaxf(sB[4], sB[5]),   m67 = fmaxf(sB[6], sB[7]);
            float m89 = fmaxf(sB[8], sB[9]),   mab = fmaxf(sB[10], sB[11]);
            float mcd = fmaxf(sB[12], sB[13]), mef = fmaxf(sB[14], sB[15]);
            float mx = fmaxf(fmaxf(fmaxf(m01, m23), fmaxf(m45, m67)),
                             fmaxf(fmaxf(m89, mab), fmaxf(mcd, mef)));
            u32x2 mr = plswap(__float_as_uint(mx), __float_as_uint(mx));
            mx = fmaxf(__uint_as_float(mr.x), __uint_as_float(mr.y));
            if (!__all(mx - mrunB <= 11.5f)) {
                float mn = fmaxf(mrunB, mx);
                float sc = exp2fast(mrunB - mn);
                mrunB = mn;
                lrunB *= sc;
                #pragma unroll
                for (int ct = 0; ct < 4; ct++)
                    #pragma unroll
                    for (int r = 0; r < 16; r++) accB[ct][r] *= sc;
            }
            float ps[8];
            #pragma unroll
            for (int r2 = 0; r2 < 8; r2++) {
                float p0 = exp2fast(sB[2 * r2]     - mrunB);
                float p1 = exp2fast(sB[2 * r2 + 1] - mrunB);
                ps[r2] = p0 + p1;
                pkrB[r2] = pk2(p0, p1);
            }
            float s01 = ps[0] + ps[1], s23 = ps[2] + ps[3];
            float s45 = ps[4] + ps[5], s67 = ps[6] + ps[7];
            float ssum = (s01 + s23) + (s45 + s67);
            u32x2 sr = plswap(__float_as_uint(ssum), __float_as_uint(ssum));
            lrunB += __uint_as_float(sr.x) + __uint_as_float(sr.y);
        }

        // ---- PV: per 16-key window, shared V frags feed both tiles
        #pragma unroll
        for (int w2 = 0; w2 < 2; w2++) {
            u32x2 rA0 = plswap(pkrA[4 * w2 + 0], pkrA[4 * w2 + 2]);
            u32x2 rA1 = plswap(pkrA[4 * w2 + 1], pkrA[4 * w2 + 3]);
            u32x4 frA; frA[0] = rA0.x; frA[1] = rA1.x; frA[2] = rA0.y; frA[3] = rA1.y;
            bf16x8 pfA = __builtin_bit_cast(bf16x8, frA);
            u32x2 rB0 = plswap(pkrB[4 * w2 + 0], pkrB[4 * w2 + 2]);
            u32x2 rB1 = plswap(pkrB[4 * w2 + 1], pkrB[4 * w2 + 3]);
            u32x4 frB; frB[0] = rB0.x; frB[1] = rB1.x; frB[2] = rB0.y; frB[3] = rB1.y;
            bf16x8 pfB = __builtin_bit_cast(bf16x8, frB);
            #pragma unroll
            for (int ct = 0; ct < 4; ct++) {
                accA[ct] = __builtin_amdgcn_mfma_f32_32x32x16_bf16(vf[w2 * 4 + ct], pfA, accA[ct], 0, 0, 0);
                accB[ct] = __builtin_amdgcn_mfma_f32_32x32x16_bf16(vf[w2 * 4 + ct], pfB, accB[ct], 0, 0, 0);
            }
        }

        kcur0 = kn0; kcur1 = kn1;
    }

    // ---- split-K combine within each ch-group (ks 3,2,1 -> ks 0), per tile
    #pragma unroll
    for (int tile = 0; tile < 2; tile++) {
        for (int sIdx = 3; sIdx >= 1; --sIdx) {
            if (ks == sIdx) {
                #pragma unroll
                for (int ct = 0; ct < 4; ct++)
                    #pragma unroll
                    for (int rr = 0; rr < 4; rr++) {
                        float4 v4;
                        if (tile == 0)
                            v4 = (float4){accA[ct][rr*4+0], accA[ct][rr*4+1], accA[ct][rr*4+2], accA[ct][rr*4+3]};
                        else
                            v4 = (float4){accB[ct][rr*4+0], accB[ct][rr*4+1], accB[ct][rr*4+2], accB[ct][rr*4+3]};
                        *(float4*)&cacc[ch][lane][ct * 16 + rr * 4] = v4;
                    }
                cml[ch][lane][0] = (tile == 0) ? mrunA : mrunB;
                cml[ch][lane][1] = (tile == 0) ? lrunA : lrunB;
            }
            __syncthreads();
            if (ks == 0) {
                float mo = cml[ch][lane][0];
                float lo = cml[ch][lane][1];
                float mr = (tile == 0) ? mrunA : mrunB;
                float mn = fmaxf(mr, mo);
                float e0 = exp2fast(mr - mn);
                float e1 = exp2fast(mo - mn);
                if (tile == 0) { mrunA = mn; lrunA = lrunA * e0 + lo * e1; }
                else           { mrunB = mn; lrunB = lrunB * e0 + lo * e1; }
                #pragma unroll
                for (int ct = 0; ct < 4; ct++)
                    #pragma unroll
                    for (int r = 0; r < 16; r++) {
                        if (tile == 0)
                            accA[ct][r] = accA[ct][r] * e0 + cacc[ch][lane][ct * 16 + r] * e1;
                        else
                            accB[ct][r] = accB[ct][r] * e0 + cacc[ch][lane][ct * 16 + r] * e1;
                    }
            }
            __syncthreads();
        }
    }

    if (ks == 0) {
        float invA = 1.0f / lrunA;
        float invB = 1.0f / lrunB;
        #pragma unroll
        for (int ct = 0; ct < 4; ct++)
            #pragma unroll
            for (int r = 0; r < 16; r++) {
                int c = ch * 128 + ct * 32 + (r & 3) + 8 * (r >> 2) + 4 * hi;
                float* ob = att + ((size_t)b * CC + c) * NP;
                ob[qt0 * 32 + q] = accA[ct][r] * invA;
                ob[qt1 * 32 + q] = accB[ct][r] * invB;
            }
    }
}

// ---------------------------------------------------------------------------
// K4: bilinear x2 upsample (half-pixel, edge clamp) + gamma * up + x, x4 vec
// ---------------------------------------------------------------------------
__global__ __launch_bounds__(256) void upsample_kernel(const float* __restrict__ att,
                                                       const float* __restrict__ x,
                                                       const float* __restrict__ gamma,
                                                       float* __restrict__ out) {
    int tid = blockIdx.x * 256 + threadIdx.x;    // B*C*H*W/4 threads
    int w4 = (tid & 31) * 4;
    int h  = (tid >> 5) & 127;
    int bc = tid >> 12;
    float g = gamma[0];

    float sh = 0.5f * h - 0.25f;
    float fhf = floorf(sh);
    float th = sh - fhf;
    int ih = (int)fhf;
    int ih0 = ih < 0 ? 0 : ih;
    int ih1 = ih + 1 > 63 ? 63 : ih + 1;
    const float* a0r = att + (size_t)bc * NP + ih0 * 64;
    const float* a1r = att + (size_t)bc * NP + ih1 * 64;

    float4 xin = *(const float4*)(x + (size_t)bc * (HH * WW) + h * WW + w4);
    float xv[4] = {xin.x, xin.y, xin.z, xin.w};
    float ov[4];
    #pragma unroll
    for (int k = 0; k < 4; k++) {
        int w = w4 + k;
        float sw = 0.5f * w - 0.25f;
        float fwf = floorf(sw);
        float tw = sw - fwf;
        int iw = (int)fwf;
        int iw0 = iw < 0 ? 0 : iw;
        int iw1 = iw + 1 > 63 ? 63 : iw + 1;
        float v00 = a0r[iw0], v01 = a0r[iw1];
        float v10 = a1r[iw0], v11 = a1r[iw1];
        float top = v00 + tw * (v01 - v00);
        float bot = v10 + tw * (v11 - v10);
        float up  = top + th * (bot - top);
        ov[k] = g * up + xv[k];
    }
    float4 o4 = {ov[0], ov[1], ov[2], ov[3]};
    *(float4*)(out + (size_t)bc * (HH * WW) + h * WW + w4) = o4;
}

// ---------------------------------------------------------------------------
extern "C" void kernel_launch(void* const* d_in, const int* in_sizes, int n_in,
                              void* d_out, int out_size, void* d_ws, size_t ws_size,
                              hipStream_t stream) {
    (void)in_sizes; (void)n_in; (void)out_size; (void)ws_size;
    const float* x     = (const float*)d_in[0];
    const float* wq    = (const float*)d_in[1];
    const float* bq    = (const float*)d_in[2];
    const float* wk    = (const float*)d_in[3];
    const float* bk    = (const float*)d_in[4];
    const float* wv    = (const float*)d_in[5];
    const float* bv    = (const float*)d_in[6];
    const float* gamma = (const float*)d_in[7];
    float* out = (float*)d_out;

    unsigned short* xfrag = (unsigned short*)d_ws;             // 4,194,304 u16 (8 MB)
    unsigned short* wfrag = xfrag + 4194304;                   // 81,920 u16 (pad to 131,072)
    unsigned short* qarr  = wfrag + 131072;                    // 524,288 u16 (1 MB)
    unsigned short* karr  = qarr + 524288;                     // 524,288 u16 (1 MB)
    unsigned short* varr  = karr + 524288;                     // 4,194,304 u16 (8 MB)
    float*          att   = (float*)(varr + 4194304);          // 4,194,304 f32 (16 MB)

    prep_kernel<<<2088, 256, 0, stream>>>(x, wq, wk, wv, xfrag, wfrag);
    projm_kernel<<<2560, 128, 0, stream>>>(xfrag, wfrag, bq, bk, bv, qarr, karr, varr);
    flash32_kernel<<<256, 512, 0, stream>>>(qarr, karr, varr, att);
    upsample_kernel<<<16384, 256, 0, stream>>>(att, x, gamma, out);
}

// Round 19
// 114.880 us; speedup vs baseline: 1.0758x; 1.0376x over previous
//
#include <hip/hip_runtime.h>

// Sizes (fixed by the problem)
#define BB 4
#define CC 256
#define HH 128
#define WW 128
#define HP 64          // pooled H, W
#define NP 4096        // HP*HP tokens per batch

#define L2E 1.4426950408889634f

typedef __attribute__((ext_vector_type(4)))  float f32x4;
typedef __attribute__((ext_vector_type(16))) float f32x16;
typedef __attribute__((ext_vector_type(8)))  short bf16x8;       // 8 bf16 in 4 VGPRs
typedef __attribute__((ext_vector_type(4)))  unsigned int u32x4;
typedef __attribute__((ext_vector_type(2)))  unsigned int u32x2;
typedef __attribute__((ext_vector_type(2)))  __bf16 bf16x2_t;

// 2^x via v_exp_f32 (native). NOT __exp2f: that name collides with glibc macros.
static __device__ __forceinline__ float exp2fast(float x) {
    return __builtin_amdgcn_exp2f(x);
}

// float -> bf16 bits, round-to-nearest-even bit-trick (used on proj/pool paths).
static __device__ __forceinline__ unsigned short f2bf(float f) {
    unsigned int u = __float_as_uint(f);
    u = (u + 0x7FFFu + ((u >> 16) & 1u)) >> 16;
    return (unsigned short)u;
}
// flash P-pack: compiler-fused v_cvt_pk_bf16_f32 (plain casts — absmax-neutral, R15).
static __device__ __forceinline__ unsigned int pk2(float a, float b) {
    bf16x2_t v = {(__bf16)a, (__bf16)b};
    return __builtin_bit_cast(unsigned int, v);
}
// lane<->lane+32 exchange on the VALU pipe (T12). BUILTIN (R17-verified):
// swap(A,B) -> (r.x, r.y) = ([A.lo;B.lo], [A.hi;B.hi]).
static __device__ __forceinline__ u32x2 plswap(unsigned int a, unsigned int b) {
    return __builtin_amdgcn_permlane32_swap(a, b, false, false);
}

// ---------------------------------------------------------------------------
// Fragment-ordered layouts (bf16):
//   xfrag[b][nt(128)][ks(16)][lane(64)][e(8)] : B-frag, X[c][n]
//   wfrag[ot(10)][ks(16)][lane(64)][e(8)]     : A-frag, W[o][c] (Q rows xL2E)
//   Q2[qtile(128)][f(2)][q(32)][hi(2)][e(8)]
//   K2[kchunk(128)][f(2)][k(32)][hi(2)][e(8)]
//   V2[kc(128)][w2(2)][ctg(8)][q(32)][hi(2)][e(8)]
// mfma_32x32x16_bf16 (m74/m101): A row=lane&31, k=(lane>>5)*8+e; B col=lane&31,
// same k; D col=lane&31, row=(r&3)+8*(r>>2)+4*(lane>>5).
// ---------------------------------------------------------------------------

// ---------------------------------------------------------------------------
// K1: fused 2x2 avg-pool + bf16 B-fragment layout, PLUS (blocks >= 2048)
// the one-time W -> A-fragment reorder (merged to save a launch).
// ---------------------------------------------------------------------------
__global__ __launch_bounds__(256) void prep_kernel(const float* __restrict__ x,
                                                   const float* __restrict__ wq,
                                                   const float* __restrict__ wk,
                                                   const float* __restrict__ wv,
                                                   unsigned short* __restrict__ xfrag,
                                                   unsigned short* __restrict__ wfrag) {
    if (blockIdx.x < 2048) {
        int tid  = blockIdx.x * 256 + threadIdx.x;   // 4*128*16*64 = 524,288 threads
        int lane = tid & 63;
        int ks   = (tid >> 6) & 15;
        int nt   = (tid >> 10) & 127;
        int b    = tid >> 17;

        int n  = nt * 32 + (lane & 31);
        int c0 = ks * 16 + (lane >> 5) * 8;
        int hp = n >> 6, wp = n & 63;

        const float* xb = x + (size_t)b * CC * (HH * WW) + (2 * hp) * WW + 2 * wp;
        unsigned short r[8];
        #pragma unroll
        for (int e = 0; e < 8; e++) {
            const float* src = xb + (size_t)(c0 + e) * (HH * WW);
            float2 a = *(const float2*)(src);
            float2 d = *(const float2*)(src + WW);
            r[e] = f2bf(0.25f * (a.x + a.y + d.x + d.y));
        }
        ushort4 lo = (ushort4){r[0], r[1], r[2], r[3]};
        ushort4 hi = (ushort4){r[4], r[5], r[6], r[7]};
        *(ushort4*)(xfrag + (size_t)tid * 8)     = lo;
        *(ushort4*)(xfrag + (size_t)tid * 8 + 4) = hi;
    } else {
        int tid  = (blockIdx.x - 2048) * 256 + threadIdx.x;   // 10*16*64 = 10,240
        if (tid >= 10240) return;
        int lane = tid & 63;
        int ks   = (tid >> 6) & 15;
        int ot   = tid >> 10;

        int o = ot * 32 + (lane & 31);
        int c = ks * 16 + (lane >> 5) * 8;
        const float* wrow;
        float scale = 1.0f;
        if (o < 32)      { wrow = wq + (size_t)o * CC;        scale = L2E; }
        else if (o < 64) { wrow = wk + (size_t)(o - 32) * CC; }
        else             { wrow = wv + (size_t)(o - 64) * CC; }
        float4 w0 = *(const float4*)(wrow + c);
        float4 w1 = *(const float4*)(wrow + c + 4);
        ushort4 lo = {f2bf(w0.x * scale), f2bf(w0.y * scale), f2bf(w0.z * scale), f2bf(w0.w * scale)};
        ushort4 hi = {f2bf(w1.x * scale), f2bf(w1.y * scale), f2bf(w1.z * scale), f2bf(w1.w * scale)};
        *(ushort4*)(wfrag + (size_t)tid * 8)     = lo;
        *(ushort4*)(wfrag + (size_t)tid * 8 + 4) = hi;
    }
}

// ---------------------------------------------------------------------------
// K2: MFMA projection GEMM. Block = 2 waves; wave computes one 32o x 32n
// tile over K=256 (16 MFMA). All operand loads are contiguous 1KB/wave.
// Epilogue adds bias and scatter-stores into Q2/K2/V2 fragment layouts.
// ---------------------------------------------------------------------------
__global__ __launch_bounds__(128) void projm_kernel(const unsigned short* __restrict__ xfrag,
                                                    const unsigned short* __restrict__ wfrag,
                                                    const float* __restrict__ bq,
                                                    const float* __restrict__ bk,
                                                    const float* __restrict__ bv,
                                                    unsigned short* __restrict__ qarr,
                                                    unsigned short* __restrict__ karr,
                                                    unsigned short* __restrict__ varr) {
    int j    = blockIdx.x;            // 4b * 128nt * 5og = 2560
    int og   = j % 5;
    int nt   = (j / 5) & 127;
    int b    = j / 640;
    int lane = threadIdx.x & 63;
    int ot   = og * 2 + (threadIdx.x >> 6);   // 0..9

    const unsigned short* abase = wfrag + ((size_t)ot * 16 * 64 + lane) * 8;
    const unsigned short* bbase = xfrag + (((size_t)(b * 128 + nt) * 16) * 64 + lane) * 8;

    f32x16 acc;
    #pragma unroll
    for (int r = 0; r < 16; r++) acc[r] = 0.f;

    #pragma unroll
    for (int ks = 0; ks < 16; ks++) {
        bf16x8 af = *(const bf16x8*)(abase + (size_t)ks * 512);
        bf16x8 bf = *(const bf16x8*)(bbase + (size_t)ks * 512);
        acc = __builtin_amdgcn_mfma_f32_32x32x16_bf16(af, bf, acc, 0, 0, 0);
    }

    int l31 = lane & 31;
    int hi2 = lane >> 5;

    if (ot == 0) {
        unsigned short* qb = qarr + (size_t)b * (NP * 32);
        #pragma unroll
        for (int r = 0; r < 16; r++) {
            int o = (r & 3) + 8 * (r >> 2) + 4 * hi2;
            float v = acc[r] + bq[o] * L2E;
            size_t idx = (((size_t)nt * 2 + (o >> 4)) * 32 + l31) * 16 + ((o >> 3) & 1) * 8 + (o & 7);
            qb[idx] = f2bf(v);
        }
    } else if (ot == 1) {
        unsigned short* kb = karr + (size_t)b * (NP * 32);
        #pragma unroll
        for (int r = 0; r < 16; r++) {
            int o = (r & 3) + 8 * (r >> 2) + 4 * hi2;
            float v = acc[r] + bk[o];
            size_t idx = (((size_t)nt * 2 + (o >> 4)) * 32 + l31) * 16 + ((o >> 3) & 1) * 8 + (o & 7);
            kb[idx] = f2bf(v);
        }
    } else {
        unsigned short* vb = varr + (size_t)b * (CC * NP);
        int kc = nt, w2 = (l31 >> 4) & 1, hiv = (l31 >> 3) & 1, ev = l31 & 7;
        size_t base = (((size_t)kc * 2 + w2) * 8) * 32 * 16 + hiv * 8 + ev;
        #pragma unroll
        for (int r = 0; r < 16; r++) {
            int c = (ot - 2) * 32 + (r & 3) + 8 * (r >> 2) + 4 * hi2;
            float v = acc[r] + bv[c];
            size_t idx = base + ((size_t)(c >> 5) * 32 + (c & 31)) * 16;
            vb[idx] = f2bf(v);
        }
    }
}

// ---------------------------------------------------------------------------
// K3: swapped-operand 32x32 MFMA flash attention, 2 q-tiles x ch-split x
// ks-split, SOFTMAX DEDUPLICATED: wave (ks,ch) computes QK^T+softmax only for
// its OWN tile (ch0->A, ch1->B); pkr[8]+sc exchanged via double-buffered LDS
// with ONE barrier per chunk. Halves the R18 duplication (VALU 47%, QK MFMA).
// V fragments still feed both tiles (halved L2 traffic, R18). Combine: owners
// publish per-ks (m,l); one-shot factors; 6 pure-add reduce rounds.
// ---------------------------------------------------------------------------
__global__ __launch_bounds__(512, 2) void flash32_kernel(const unsigned short* __restrict__ qarr,
                                                         const unsigned short* __restrict__ karr,
                                                         const unsigned short* __restrict__ varr,
                                                         float* __restrict__ att) {
    __shared__ float exch[2][4][2][64][9];   // [dbuf][ks][ch][lane][pkr8+sc] = 18KB
    __shared__ float cacc[2][64][68];        // combine acc transfer, per ch-group
    __shared__ float cmlT[2][4][64][2];      // [tile][ks][lane][m,l]
    int t    = threadIdx.x;
    int lane = t & 63;
    int w    = t >> 6;                 // 0..7
    int ch   = w & 1;                  // channel half (also: tile ownership)
    int ks   = w >> 1;                 // key quarter
    int j    = blockIdx.x;
    int b    = j & 3;                  // batch -> XCD pinning
    int st   = j >> 2;                 // 0..63 q-supertile (64 rows)
    int qt0  = st * 2, qt1 = qt0 + 1;
    int qtOwn = qt0 + ch;              // own tile's q-tile index

    const unsigned short* qb2 = qarr + (size_t)b * (NP * 32);
    const unsigned short* kb2 = karr + (size_t)b * (NP * 32);
    const unsigned short* vb2 = varr + (size_t)b * (CC * NP);

    int q  = lane & 31;
    int hi = lane >> 5;
    int lq16 = (q * 2 + hi) * 8;       // lane's 16B slot within a 1KB fragment block

    // Q frags for OWN tile only
    bf16x8 qf0 = *(const bf16x8*)(qb2 + (size_t)(qtOwn * 2 + 0) * 512 + lq16);
    bf16x8 qf1 = *(const bf16x8*)(qb2 + (size_t)(qtOwn * 2 + 1) * 512 + lq16);

    f32x16 accA[4], accB[4];           // tile A/B x own 128-ch half
    #pragma unroll
    for (int ct = 0; ct < 4; ct++)
        #pragma unroll
        for (int r = 0; r < 16; r++) { accA[ct][r] = 0.f; accB[ct][r] = 0.f; }
    float mrun = -3.0e38f, lrun = 0.f; // own tile's softmax state

    const f32x16 z16 = {0.f,0.f,0.f,0.f,0.f,0.f,0.f,0.f,0.f,0.f,0.f,0.f,0.f,0.f,0.f,0.f};

    // ---- prologue: K frags for first chunk
    int kc0 = ks * 32;
    const unsigned short* kcp0 = kb2 + (size_t)kc0 * 1024 + lq16;
    bf16x8 kcur0 = *(const bf16x8*)(kcp0);
    bf16x8 kcur1 = *(const bf16x8*)(kcp0 + 512);

    for (int kci = 0; kci < 32; ++kci) {
        int kcidx = kc0 + kci;
        int nid = (kci < 31) ? (kcidx + 1) : kcidx;
        int p = kci & 1;

        // ---- V frags for THIS chunk, own 128-ch half (consumed at PV)
        const unsigned short* vcp = vb2 + ((size_t)kcidx * 16 + ch * 4) * 512 + lq16;
        bf16x8 vf[8];
        #pragma unroll
        for (int w2 = 0; w2 < 2; w2++)
            #pragma unroll
            for (int i = 0; i < 4; i++)
                vf[w2 * 4 + i] = *(const bf16x8*)(vcp + (size_t)(w2 * 8 + i) * 512);

        // ---- K loads for NEXT chunk
        const unsigned short* kn = kb2 + (size_t)nid * 1024 + lq16;
        bf16x8 kn0 = *(const bf16x8*)(kn);
        bf16x8 kn1 = *(const bf16x8*)(kn + 512);

        // ---- QK^T swapped, OWN tile only
        f32x16 s = __builtin_amdgcn_mfma_f32_32x32x16_bf16(kcur0, qf0, z16, 0, 0, 0);
        s = __builtin_amdgcn_mfma_f32_32x32x16_bf16(kcur1, qf1, s, 0, 0, 0);

        // ---- softmax own tile (permlane + defer-max + cvt_pk + tree-sum)
        unsigned int pkr[8];
        float sc = 1.0f;
        {
            float m01 = fmaxf(s[0], s[1]),   m23 = fmaxf(s[2], s[3]);
            float m45 = fmaxf(s[4], s[5]),   m67 = fmaxf(s[6], s[7]);
            float m89 = fmaxf(s[8], s[9]),   mab = fmaxf(s[10], s[11]);
            float mcd = fmaxf(s[12], s[13]), mef = fmaxf(s[14], s[15]);
            float mx = fmaxf(fmaxf(fmaxf(m01, m23), fmaxf(m45, m67)),
                             fmaxf(fmaxf(m89, mab), fmaxf(mcd, mef)));
            u32x2 mr = plswap(__float_as_uint(mx), __float_as_uint(mx));
            mx = fmaxf(__uint_as_float(mr.x), __uint_as_float(mr.y));
            if (!__all(mx - mrun <= 11.5f)) {
                float mn = fmaxf(mrun, mx);
                sc = exp2fast(mrun - mn);
                mrun = mn;
                lrun *= sc;
            }
            float ps[8];
            #pragma unroll
            for (int r2 = 0; r2 < 8; r2++) {
                float p0 = exp2fast(s[2 * r2]     - mrun);
                float p1 = exp2fast(s[2 * r2 + 1] - mrun);
                ps[r2] = p0 + p1;
                pkr[r2] = pk2(p0, p1);
            }
            float s01 = ps[0] + ps[1], s23 = ps[2] + ps[3];
            float s45 = ps[4] + ps[5], s67 = ps[6] + ps[7];
            float ssum = (s01 + s23) + (s45 + s67);
            u32x2 sr = plswap(__float_as_uint(ssum), __float_as_uint(ssum));
            lrun += __uint_as_float(sr.x) + __uint_as_float(sr.y);
        }

        // ---- exchange: publish own {pkr, sc}; read partner's
        {
            float* slot = exch[p][ks][ch][lane];
            #pragma unroll
            for (int i = 0; i < 8; i++) slot[i] = __uint_as_float(pkr[i]);
            slot[8] = sc;
        }
        __syncthreads();
        unsigned int pkrO[8];
        float scO;
        {
            const float* oth = exch[p][ks][ch ^ 1][lane];
            #pragma unroll
            for (int i = 0; i < 8; i++) pkrO[i] = __float_as_uint(oth[i]);
            scO = oth[8];
        }

        // ---- map to tiles (ch wave-uniform)
        unsigned int pkrA[8], pkrB[8];
        float scA, scB;
        if (ch == 0) {
            #pragma unroll
            for (int i = 0; i < 8; i++) { pkrA[i] = pkr[i]; pkrB[i] = pkrO[i]; }
            scA = sc; scB = scO;
        } else {
            #pragma unroll
            for (int i = 0; i < 8; i++) { pkrA[i] = pkrO[i]; pkrB[i] = pkr[i]; }
            scA = scO; scB = sc;
        }

        // ---- rescale accs (wave-uniform triggers)
        if (!__all(scA == 1.0f)) {
            #pragma unroll
            for (int ct = 0; ct < 4; ct++)
                #pragma unroll
                for (int r = 0; r < 16; r++) accA[ct][r] *= scA;
        }
        if (!__all(scB == 1.0f)) {
            #pragma unroll
            for (int ct = 0; ct < 4; ct++)
                #pragma unroll
                for (int r = 0; r < 16; r++) accB[ct][r] *= scB;
        }

        // ---- PV: per 16-key window, shared V frags feed both tiles
        #pragma unroll
        for (int w2 = 0; w2 < 2; w2++) {
            u32x2 rA0 = plswap(pkrA[4 * w2 + 0], pkrA[4 * w2 + 2]);
            u32x2 rA1 = plswap(pkrA[4 * w2 + 1], pkrA[4 * w2 + 3]);
            u32x4 frA; frA[0] = rA0.x; frA[1] = rA1.x; frA[2] = rA0.y; frA[3] = rA1.y;
            bf16x8 pfA = __builtin_bit_cast(bf16x8, frA);
            u32x2 rB0 = plswap(pkrB[4 * w2 + 0], pkrB[4 * w2 + 2]);
            u32x2 rB1 = plswap(pkrB[4 * w2 + 1], pkrB[4 * w2 + 3]);
            u32x4 frB; frB[0] = rB0.x; frB[1] = rB1.x; frB[2] = rB0.y; frB[3] = rB1.y;
            bf16x8 pfB = __builtin_bit_cast(bf16x8, frB);
            #pragma unroll
            for (int ct = 0; ct < 4; ct++) {
                accA[ct] = __builtin_amdgcn_mfma_f32_32x32x16_bf16(vf[w2 * 4 + ct], pfA, accA[ct], 0, 0, 0);
                accB[ct] = __builtin_amdgcn_mfma_f32_32x32x16_bf16(vf[w2 * 4 + ct], pfB, accB[ct], 0, 0, 0);
            }
        }

        kcur0 = kn0; kcur1 = kn1;
    }

    // ---- combine: owners publish per-ks (m,l); everyone derives one-shot factors
    cmlT[ch][ks][lane][0] = mrun;
    cmlT[ch][ks][lane][1] = lrun;
    __syncthreads();
    float eA[4], eB[4], invA, invB;
    {
        float mA = fmaxf(fmaxf(cmlT[0][0][lane][0], cmlT[0][1][lane][0]),
                         fmaxf(cmlT[0][2][lane][0], cmlT[0][3][lane][0]));
        float mB = fmaxf(fmaxf(cmlT[1][0][lane][0], cmlT[1][1][lane][0]),
                         fmaxf(cmlT[1][2][lane][0], cmlT[1][3][lane][0]));
        float lA = 0.f, lB = 0.f;
        #pragma unroll
        for (int sI = 0; sI < 4; sI++) {
            eA[sI] = exp2fast(cmlT[0][sI][lane][0] - mA);
            eB[sI] = exp2fast(cmlT[1][sI][lane][0] - mB);
            lA += cmlT[0][sI][lane][1] * eA[sI];
            lB += cmlT[1][sI][lane][1] * eB[sI];
        }
        invA = 1.0f / lA;
        invB = 1.0f / lB;
    }
    // scale own acc by own ks factor
    #pragma unroll
    for (int ct = 0; ct < 4; ct++)
        #pragma unroll
        for (int r = 0; r < 16; r++) { accA[ct][r] *= eA[ks]; accB[ct][r] *= eB[ks]; }

    // pure-add reduce across ks within each ch group, tile A then tile B
    #pragma unroll
    for (int tile = 0; tile < 2; tile++) {
        for (int sIdx = 3; sIdx >= 1; --sIdx) {
            if (ks == sIdx) {
                #pragma unroll
                for (int ct = 0; ct < 4; ct++)
                    #pragma unroll
                    for (int rr = 0; rr < 4; rr++) {
                        float4 v4;
                        if (tile == 0)
                            v4 = (float4){accA[ct][rr*4+0], accA[ct][rr*4+1], accA[ct][rr*4+2], accA[ct][rr*4+3]};
                        else
                            v4 = (float4){accB[ct][rr*4+0], accB[ct][rr*4+1], accB[ct][rr*4+2], accB[ct][rr*4+3]};
                        *(float4*)&cacc[ch][lane][ct * 16 + rr * 4] = v4;
                    }
            }
            __syncthreads();
            if (ks == 0) {
                #pragma unroll
                for (int ct = 0; ct < 4; ct++)
                    #pragma unroll
                    for (int r = 0; r < 16; r++) {
                        if (tile == 0) accA[ct][r] += cacc[ch][lane][ct * 16 + r];
                        else           accB[ct][r] += cacc[ch][lane][ct * 16 + r];
                    }
            }
            __syncthreads();
        }
    }

    if (ks == 0) {
        #pragma unroll
        for (int ct = 0; ct < 4; ct++)
            #pragma unroll
            for (int r = 0; r < 16; r++) {
                int c = ch * 128 + ct * 32 + (r & 3) + 8 * (r >> 2) + 4 * hi;
                float* ob = att + ((size_t)b * CC + c) * NP;
                ob[qt0 * 32 + q] = accA[ct][r] * invA;
                ob[qt1 * 32 + q] = accB[ct][r] * invB;
            }
    }
}

// ---------------------------------------------------------------------------
// K4: bilinear x2 upsample (half-pixel, edge clamp) + gamma * up + x, x4 vec
// ---------------------------------------------------------------------------
__global__ __launch_bounds__(256) void upsample_kernel(const float* __restrict__ att,
                                                       const float* __restrict__ x,
                                                       const float* __restrict__ gamma,
                                                       float* __restrict__ out) {
    int tid = blockIdx.x * 256 + threadIdx.x;    // B*C*H*W/4 threads
    int w4 = (tid & 31) * 4;
    int h  = (tid >> 5) & 127;
    int bc = tid >> 12;
    float g = gamma[0];

    float sh = 0.5f * h - 0.25f;
    float fhf = floorf(sh);
    float th = sh - fhf;
    int ih = (int)fhf;
    int ih0 = ih < 0 ? 0 : ih;
    int ih1 = ih + 1 > 63 ? 63 : ih + 1;
    const float* a0r = att + (size_t)bc * NP + ih0 * 64;
    const float* a1r = att + (size_t)bc * NP + ih1 * 64;

    float4 xin = *(const float4*)(x + (size_t)bc * (HH * WW) + h * WW + w4);
    float xv[4] = {xin.x, xin.y, xin.z, xin.w};
    float ov[4];
    #pragma unroll
    for (int k = 0; k < 4; k++) {
        int w = w4 + k;
        float sw = 0.5f * w - 0.25f;
        float fwf = floorf(sw);
        float tw = sw - fwf;
        int iw = (int)fwf;
        int iw0 = iw < 0 ? 0 : iw;
        int iw1 = iw + 1 > 63 ? 63 : iw + 1;
        float v00 = a0r[iw0], v01 = a0r[iw1];
        float v10 = a1r[iw0], v11 = a1r[iw1];
        float top = v00 + tw * (v01 - v00);
        float bot = v10 + tw * (v11 - v10);
        float up  = top + th * (bot - top);
        ov[k] = g * up + xv[k];
    }
    float4 o4 = {ov[0], ov[1], ov[2], ov[3]};
    *(float4*)(out + (size_t)bc * (HH * WW) + h * WW + w4) = o4;
}

// ---------------------------------------------------------------------------
extern "C" void kernel_launch(void* const* d_in, const int* in_sizes, int n_in,
                              void* d_out, int out_size, void* d_ws, size_t ws_size,
                              hipStream_t stream) {
    (void)in_sizes; (void)n_in; (void)out_size; (void)ws_size;
    const float* x     = (const float*)d_in[0];
    const float* wq    = (const float*)d_in[1];
    const float* bq    = (const float*)d_in[2];
    const float* wk    = (const float*)d_in[3];
    const float* bk    = (const float*)d_in[4];
    const float* wv    = (const float*)d_in[5];
    const float* bv    = (const float*)d_in[6];
    const float* gamma = (const float*)d_in[7];
    float* out = (float*)d_out;

    unsigned short* xfrag = (unsigned short*)d_ws;             // 4,194,304 u16 (8 MB)
    unsigned short* wfrag = xfrag + 4194304;                   // 81,920 u16 (pad to 131,072)
    unsigned short* qarr  = wfrag + 131072;                    // 524,288 u16 (1 MB)
    unsigned short* karr  = qarr + 524288;                     // 524,288 u16 (1 MB)
    unsigned short* varr  = karr + 524288;                     // 4,194,304 u16 (8 MB)
    float*          att   = (float*)(varr + 4194304);          // 4,194,304 f32 (16 MB)

    prep_kernel<<<2088, 256, 0, stream>>>(x, wq, wk, wv, xfrag, wfrag);
    projm_kernel<<<2560, 128, 0, stream>>>(xfrag, wfrag, bq, bk, bv, qarr, karr, varr);
    flash32_kernel<<<256, 512, 0, stream>>>(qarr, karr, varr, att);
    upsample_kernel<<<16384, 256, 0, stream>>>(att, x, gamma, out);
}